// Round 6
// baseline (363.325 us; speedup 1.0000x reference)
//
#include <hip/hip_runtime.h>
#include <hip/hip_bf16.h>
#include <cstdint>
#include <cstddef>

// ---------------------------------------------------------------------------
// GraphSAGE 3-layer encoder. MFMA GEMM (LDS-free, weight-stationary,
// operand-swapped for wide stores) + counting-sort CSR build + gather-mean agg.
// Per layer (fused): [P | Q] = A @ [Wl | Wr] via bf16 MFMA (f32 accum)
//   P -> bf16 (gather operand); Q -> bf16 (layers 1,2) / f32 (layer 3)
//   out = act( inv_deg * segsum(P[src]) + Q )
// Swapped mfma(b,a): D^T layout -> lane holds 4 consecutive cols of one row
// -> 8B packed bf16 stores instead of 2B scalar stores.
// ---------------------------------------------------------------------------

typedef __attribute__((ext_vector_type(8))) short bf16x8;
typedef __attribute__((ext_vector_type(4))) float f32x4;

__device__ __forceinline__ short f2bf(float f) {
  uint32_t u = __builtin_bit_cast(uint32_t, f);
  u += 0x7fffu + ((u >> 16) & 1u);
  return (short)(u >> 16);
}
__device__ __forceinline__ float bflo(uint32_t u) {
  union { uint32_t i; float f; } v; v.i = u << 16; return v.f;
}
__device__ __forceinline__ float bfhi(uint32_t u) {
  union { uint32_t i; float f; } v; v.i = u & 0xffff0000u; return v.f;
}
__device__ __forceinline__ uint32_t pkbf(float a, float b) {
  return (uint32_t)(uint16_t)f2bf(a) | ((uint32_t)(uint16_t)f2bf(b) << 16);
}

// ---------- int64-vs-int32 edge index detection ----------
__global__ void k_detect(const int* __restrict__ ei, int* __restrict__ flag, int E) {
  int t = threadIdx.x;
  int stride = E / 4096; if (stride < 1) stride = 1;
  int found = 0;
  for (int i = t; i < 4096; i += 256) {
    long long e = (long long)i * stride;
    if (e < E && ei[2 * e + 1] != 0) found = 1;
  }
  if (found) atomicOr(flag, 1);
}

__device__ __forceinline__ int edge_val(const int* ei, int is64, size_t pos) {
  return is64 ? ei[2 * pos] : ei[pos];
}

// ============================ counting-sort CSR =============================
#define GPART 256

__global__ __launch_bounds__(256)
void k_bhist(const int* __restrict__ ei, const int* __restrict__ flag,
             int* __restrict__ hist, int E, int NB, int CPB) {
  __shared__ int lh[1024];
  int g = blockIdx.x, t = threadIdx.x;
  for (int b = t; b < NB; b += 256) lh[b] = 0;
  __syncthreads();
  int is64 = (*flag == 0);
  int e0 = g * CPB, e1 = min(e0 + CPB, E);
  for (int e = e0 + t; e < e1; e += 256) {
    int d = edge_val(ei, is64, (size_t)E + e);
    atomicAdd(&lh[d >> 7], 1);
  }
  __syncthreads();
  for (int b = t; b < NB; b += 256) hist[(size_t)g * NB + b] = lh[b];
}

__global__ void k_csum(const int* __restrict__ hist, int* __restrict__ total,
                       int NB, int G) {
  int b = blockIdx.x, t = threadIdx.x;
  int s = 0;
  for (int g = t; g < G; g += 64) s += hist[(size_t)g * NB + b];
  for (int off = 32; off; off >>= 1) s += __shfl_down(s, off);
  if (t == 0) total[b] = s;
}

__global__ void k_bscan(const int* __restrict__ total, int* __restrict__ bbase,
                        int NB) {
  __shared__ int sh[1024];
  int t = threadIdx.x;
  int v = (t < NB) ? total[t] : 0;
  sh[t] = v; __syncthreads();
  for (int off = 1; off < 1024; off <<= 1) {
    int x = (t >= off) ? sh[t - off] : 0;
    __syncthreads();
    sh[t] += x;
    __syncthreads();
  }
  if (t < NB) bbase[t] = sh[t] - v;
  if (t == NB - 1) bbase[NB] = sh[t];
}

__global__ void k_coff(int* __restrict__ hist, const int* __restrict__ bbase,
                       int NB, int G) {
  int b = blockIdx.x, t = threadIdx.x;
  int carry = bbase[b];
  for (int g0 = 0; g0 < G; g0 += 64) {
    int v = hist[(size_t)(g0 + t) * NB + b];
    int incl = v;
    #pragma unroll
    for (int off = 1; off < 64; off <<= 1) {
      int x = __shfl_up(incl, off);
      if (t >= off) incl += x;
    }
    hist[(size_t)(g0 + t) * NB + b] = carry + incl - v;
    carry += __shfl(incl, 63);
  }
}

__global__ __launch_bounds__(256)
void k_bscatter(const int* __restrict__ ei, const int* __restrict__ flag,
                const int* __restrict__ off, uint32_t* __restrict__ staging,
                int E, int NB, int CPB) {
  __shared__ int lcur[1024];
  int g = blockIdx.x, t = threadIdx.x;
  for (int b = t; b < NB; b += 256) lcur[b] = off[(size_t)g * NB + b];
  __syncthreads();
  int is64 = (*flag == 0);
  int e0 = g * CPB, e1 = min(e0 + CPB, E);
  for (int e = e0 + t; e < e1; e += 256) {
    int s = edge_val(ei, is64, (size_t)e);
    int d = edge_val(ei, is64, (size_t)E + e);
    int p = atomicAdd(&lcur[d >> 7], 1);
    staging[p] = ((uint32_t)(d & 127) << 25) | (uint32_t)s;
  }
}

#define LDSCAP 12288
__global__ __launch_bounds__(256)
void k_bfinal(const uint32_t* __restrict__ staging, const int* __restrict__ bbase,
              int* __restrict__ row_start, int* __restrict__ sorted_src,
              int N, int NB, int E) {
  __shared__ uint32_t ent[LDSCAP];
  __shared__ int cnt[128];
  __shared__ int pre[128];
  int b = blockIdx.x, t = threadIdx.x;
  int base = bbase[b], sz = bbase[b + 1] - base;
  int n0 = b << 7;
  if (t < 128) cnt[t] = 0;
  __syncthreads();
  bool fit = (sz <= LDSCAP);
  if (fit) {
    for (int i = t; i < sz; i += 256) {
      uint32_t u = staging[base + i];
      ent[i] = u;
      atomicAdd(&cnt[u >> 25], 1);
    }
  } else {
    for (int i = t; i < sz; i += 256)
      atomicAdd(&cnt[staging[base + i] >> 25], 1);
  }
  __syncthreads();
  if (t < 128) pre[t] = cnt[t];
  __syncthreads();
  #pragma unroll
  for (int off = 1; off < 128; off <<= 1) {
    int x = (t < 128 && t >= off) ? pre[t - off] : 0;
    __syncthreads();
    if (t < 128) pre[t] += x;
    __syncthreads();
  }
  int nn = N - n0; if (nn > 128) nn = 128;
  if (t < 128) {
    int ex = pre[t] - cnt[t];
    if (t < nn) row_start[n0 + t] = base + ex;
    cnt[t] = ex;
  }
  if (b == NB - 1 && t == 0) row_start[N] = E;
  __syncthreads();
  if (fit) {
    for (int i = t; i < sz; i += 256) {
      uint32_t u = ent[i];
      int p = atomicAdd(&cnt[u >> 25], 1);
      sorted_src[base + p] = (int)(u & 0x1FFFFFFu);
    }
  } else {
    for (int i = t; i < sz; i += 256) {
      uint32_t u = staging[base + i];
      int p = atomicAdd(&cnt[u >> 25], 1);
      sorted_src[base + p] = (int)(u & 0x1FFFFFFu);
    }
  }
}

// ---------- weight prep: Wt[c][k] (bf16, transposed, zero-padded) ----------
__global__ void k_wprep(const float* __restrict__ Wl, const float* __restrict__ Wr,
                        short* __restrict__ Wt, int K, int H, int Hp, int Kp, int NP) {
  int idx = blockIdx.x * 256 + threadIdx.x;
  if (idx >= NP * Kp) return;
  int c = idx / Kp, k = idx - c * Kp;
  float v = 0.f;
  if (k < K) {
    if (c < H) v = Wl[(size_t)k * H + c];
    else if (c >= Hp && c - Hp < H) v = Wr[(size_t)k * H + (c - Hp)];
  }
  Wt[idx] = f2bf(v);
}

// ---------- LDS-free MFMA GEMM (operand-swapped): [P|Q] = A @ Wt^T ----------
// MODE 0: A f32 (cvt in regs); MODE 1: A bf16. Stride lda elements.
// Swapped mfma(b_weights, a_nodes, acc): lane holds node = lane&15 of the
// 16-row frag, cols (lane>>4)*4 + r (4 consecutive) -> 8B/16B stores.
template<int MODE, int NKS, int QBF16>
__global__ __launch_bounds__(256, 4)
void k_gemm2(const void* __restrict__ Av, const short* __restrict__ Wt,
             const float* __restrict__ bias, short* __restrict__ P,
             void* __restrict__ Qv, int M, int lda, int H, int Hp, int F) {
  const int Kp = NKS * 32;
  int t = threadIdx.x;
  int wv = t >> 6, lane = t & 63;
  int l16 = lane & 15, lk8 = (lane >> 4) * 8;
  int m0 = blockIdx.x * 64;
  int f0 = blockIdx.y * 8 + wv * 2;
  int nf = F - f0; nf = nf < 0 ? 0 : (nf > 2 ? 2 : nf);
  if (nf == 0) return;

  // B fragments (weights) + per-lane 4-col store chunk metadata
  bf16x8 b[2][NKS];
  float4 bia[2];
  int cbase[2]; bool isPc[2]; bool cok[2];
  #pragma unroll
  for (int cf = 0; cf < 2; cf++) {
    int cfrag = f0 + cf;
    bool p = cfrag * 16 < Hp;
    int cb = cfrag * 16 + ((lane >> 4) << 2) - (p ? 0 : Hp);
    cbase[cf] = cb; isPc[cf] = p;
    cok[cf] = (cf < nf) && (cb < H);
    bia[cf] = make_float4(0.f, 0.f, 0.f, 0.f);
    if (cok[cf] && !p) bia[cf] = *(const float4*)(bias + cb);
    if (cf < nf) {
      const short* wp = Wt + (size_t)(cfrag * 16 + l16) * Kp + lk8;
      #pragma unroll
      for (int ks = 0; ks < NKS; ks++)
        b[cf][ks] = *(const bf16x8*)(wp + ks * 32);
    }
  }

  #pragma unroll
  for (int rf = 0; rf < 4; rf++) {
    int node = m0 + rf * 16 + l16;
    bool rok = node < M;
    bf16x8 a[NKS];
    if (MODE == 0) {
      const float* ap = (const float*)Av + (size_t)node * lda + lk8;
      #pragma unroll
      for (int ks = 0; ks < NKS; ks++) {
        if (rok) {
          float4 v0 = *(const float4*)(ap + ks * 32);
          float4 v1 = *(const float4*)(ap + ks * 32 + 4);
          bf16x8 r;
          r[0] = f2bf(v0.x); r[1] = f2bf(v0.y); r[2] = f2bf(v0.z); r[3] = f2bf(v0.w);
          r[4] = f2bf(v1.x); r[5] = f2bf(v1.y); r[6] = f2bf(v1.z); r[7] = f2bf(v1.w);
          a[ks] = r;
        } else {
          a[ks] = (bf16x8){0, 0, 0, 0, 0, 0, 0, 0};
        }
      }
    } else {
      const short* ap = (const short*)Av + (size_t)node * lda + lk8;
      #pragma unroll
      for (int ks = 0; ks < NKS; ks++)
        a[ks] = rok ? *(const bf16x8*)(ap + ks * 32)
                    : (bf16x8){0, 0, 0, 0, 0, 0, 0, 0};
    }

    f32x4 acc[2];
    acc[0] = (f32x4){0.f, 0.f, 0.f, 0.f};
    acc[1] = (f32x4){0.f, 0.f, 0.f, 0.f};
    #pragma unroll
    for (int ks = 0; ks < NKS; ks++) {
      #pragma unroll
      for (int cf = 0; cf < 2; cf++) {
        if (cf < nf)   // SWAPPED operands: D^T layout
          acc[cf] = __builtin_amdgcn_mfma_f32_16x16x32_bf16(b[cf][ks], a[ks], acc[cf], 0, 0, 0);
      }
    }

    if (rok) {
      #pragma unroll
      for (int cf = 0; cf < 2; cf++) {
        if (cok[cf]) {
          if (isPc[cf]) {
            uint2 pk;
            pk.x = pkbf(acc[cf][0], acc[cf][1]);
            pk.y = pkbf(acc[cf][2], acc[cf][3]);
            *(uint2*)(P + (size_t)node * H + cbase[cf]) = pk;
          } else if (QBF16) {
            uint2 pk;
            pk.x = pkbf(acc[cf][0] + bia[cf].x, acc[cf][1] + bia[cf].y);
            pk.y = pkbf(acc[cf][2] + bia[cf].z, acc[cf][3] + bia[cf].w);
            *(uint2*)((short*)Qv + (size_t)node * H + cbase[cf]) = pk;
          } else {
            float4 r;
            r.x = acc[cf][0] + bia[cf].x; r.y = acc[cf][1] + bia[cf].y;
            r.z = acc[cf][2] + bia[cf].z; r.w = acc[cf][3] + bia[cf].w;
            *(float4*)((float*)Qv + (size_t)node * H + cbase[cf]) = r;
          }
        }
      }
    }
  }
}

// ---------- aggregation: out = act( scale * sum_{e} bf16 P[src_e] + Q ) ------
template<int RELU, int PACK, int OUTBF16, int QBF16>
__global__ __launch_bounds__(256)
void k_agg(const short* __restrict__ P, const void* Q,
           const int* __restrict__ rs, const int* __restrict__ srcs,
           void* out, int N, int H, int HSo) {
  int wave = threadIdx.x >> 6;
  int lane = threadIdx.x & 63;
  int node = blockIdx.x * 4 + wave;
  if (node >= N) return;
  int start = rs[node];
  int deg = rs[node + 1] - start;
  int c = lane * PACK;
  bool act = c < H;
  float a0 = 0.f, a1 = 0.f;
  const int* sp = srcs + start;

  for (int base = 0; base < deg; base += 64) {
    int cnt = deg - base; if (cnt > 64) cnt = 64;
    int myidx = (lane < cnt) ? sp[base + lane] : 0;
    int e = 0;
    int nfull = cnt & ~3;
    for (; e < nfull; e += 4) {
      int s0 = __shfl(myidx, e);
      int s1 = __shfl(myidx, e + 1);
      int s2 = __shfl(myidx, e + 2);
      int s3 = __shfl(myidx, e + 3);
      if (act) {
        if (PACK == 2) {
          uint32_t u0 = *(const uint32_t*)(P + (size_t)s0 * H + c);
          uint32_t u1 = *(const uint32_t*)(P + (size_t)s1 * H + c);
          uint32_t u2 = *(const uint32_t*)(P + (size_t)s2 * H + c);
          uint32_t u3 = *(const uint32_t*)(P + (size_t)s3 * H + c);
          a0 += bflo(u0); a1 += bfhi(u0);
          a0 += bflo(u1); a1 += bfhi(u1);
          a0 += bflo(u2); a1 += bfhi(u2);
          a0 += bflo(u3); a1 += bfhi(u3);
        } else {
          uint32_t u0 = *(const uint16_t*)(P + (size_t)s0 * H + c);
          uint32_t u1 = *(const uint16_t*)(P + (size_t)s1 * H + c);
          uint32_t u2 = *(const uint16_t*)(P + (size_t)s2 * H + c);
          uint32_t u3 = *(const uint16_t*)(P + (size_t)s3 * H + c);
          a0 += bflo(u0) + bflo(u1) + bflo(u2) + bflo(u3);
        }
      }
    }
    for (; e < cnt; ++e) {
      int s0 = __shfl(myidx, e);
      if (act) {
        if (PACK == 2) {
          uint32_t u0 = *(const uint32_t*)(P + (size_t)s0 * H + c);
          a0 += bflo(u0); a1 += bfhi(u0);
        } else {
          uint32_t u0 = *(const uint16_t*)(P + (size_t)s0 * H + c);
          a0 += bflo(u0);
        }
      }
    }
  }

  if (!act) return;
  float scale = 1.f / (float)(deg > 0 ? deg : 1);
  size_t oq = (size_t)node * H + c;
  size_t oo = (size_t)node * HSo + c;
  if (PACK == 2) {
    float q0, q1;
    if (QBF16) {
      uint32_t qu = *(const uint32_t*)((const short*)Q + oq);
      q0 = bflo(qu); q1 = bfhi(qu);
    } else {
      float2 q = *(const float2*)((const float*)Q + oq);
      q0 = q.x; q1 = q.y;
    }
    float v0 = a0 * scale + q0;
    float v1 = a1 * scale + q1;
    if (RELU) { v0 = fmaxf(v0, 0.f); v1 = fmaxf(v1, 0.f); }
    if (OUTBF16) {
      *(uint32_t*)((short*)out + oo) = pkbf(v0, v1);
    } else {
      float2 r; r.x = v0; r.y = v1;
      *(float2*)((float*)out + oo) = r;
    }
  } else {
    float q0;
    if (QBF16) q0 = bflo(*(const uint16_t*)((const short*)Q + oq));
    else       q0 = ((const float*)Q)[oq];
    float v0 = a0 * scale + q0;
    if (RELU) v0 = fmaxf(v0, 0.f);
    if (OUTBF16) ((short*)out)[oo] = f2bf(v0);
    else ((float*)out)[oo] = v0;
  }
}

// ---------------------------------------------------------------------------
extern "C" void kernel_launch(void* const* d_in, const int* in_sizes, int n_in,
                              void* d_out, int out_size, void* d_ws, size_t ws_size,
                              hipStream_t stream) {
  const float* x   = (const float*)d_in[0];
  const int*   ei  = (const int*)d_in[1];
  const float* Wl1 = (const float*)d_in[2];
  const float* Wr1 = (const float*)d_in[3];
  const float* b1  = (const float*)d_in[4];
  const float* Wl2 = (const float*)d_in[5];
  const float* Wr2 = (const float*)d_in[6];
  const float* b2  = (const float*)d_in[7];
  const float* Wl3 = (const float*)d_in[8];
  const float* Wr3 = (const float*)d_in[9];
  const float* b3  = (const float*)d_in[10];

  const int DIN = 128;
  const int N  = in_sizes[0] / DIN;   // 100000
  const int E  = in_sizes[1] / 2;     // 1600000
  const int H1 = in_sizes[4];         // 128
  const int H2 = in_sizes[7];         // 76
  const int H3 = in_sizes[10];        // 64
  const int Hp1 = 128, Hp2 = 80, Hp3 = 64;
  const int Kp12 = 128, Kp3 = 96;
  const int NB = (N + 127) >> 7;
  const int G = GPART;
  const int CPB = (E + G - 1) / G;

  // ---- workspace carve ----
  char* w = (char*)d_ws;
  auto alloc = [&](size_t bytes) {
    char* p = w;
    w += (bytes + 255) & ~(size_t)255;
    return p;
  };
  short* bufP  = (short*)alloc((size_t)N * 128 * 2);   // P (bf16)
  short* bufH1 = (short*)alloc((size_t)N * 128 * 2);   // h1 (bf16, stride 128)
  short* bufH2 = (short*)alloc((size_t)N * 96 * 2);    // h2 (bf16, stride 96=Kp3)
  short* q1    = (short*)alloc((size_t)N * 128 * 2);   // Q1 (bf16)
  short* q2    = (short*)alloc((size_t)N * 76 * 2);    // Q2 (bf16)
  float* q3    = (float*)alloc((size_t)N * 64 * 4);    // Q3 (f32)
  short* Wt1   = (short*)alloc((size_t)256 * 128 * 2);
  short* Wt2   = (short*)alloc((size_t)160 * 128 * 2);
  short* Wt3   = (short*)alloc((size_t)128 * 96 * 2);
  int* row_start = (int*)alloc((size_t)(N + 1) * 4);
  int* hist      = (int*)alloc((size_t)G * NB * 4);
  int* total     = (int*)alloc((size_t)NB * 4);
  int* bbase     = (int*)alloc((size_t)(NB + 1) * 4);
  uint32_t* staging = (uint32_t*)alloc((size_t)E * 4);
  int* sorted    = (int*)alloc((size_t)E * 4);
  int* flag      = (int*)alloc(256);

  // ---- weight prep ----
  k_wprep<<<(256 * 128 + 255) / 256, 256, 0, stream>>>(Wl1, Wr1, Wt1, DIN, H1, Hp1, Kp12, 2 * Hp1);
  k_wprep<<<(160 * 128 + 255) / 256, 256, 0, stream>>>(Wl2, Wr2, Wt2, H1, H2, Hp2, Kp12, 2 * Hp2);
  k_wprep<<<(128 * 96 + 255) / 256, 256, 0, stream>>>(Wl3, Wr3, Wt3, H2, H3, Hp3, Kp3, 2 * Hp3);

  // ---- CSR build (counting sort) ----
  hipMemsetAsync(flag, 0, 4, stream);
  k_detect<<<1, 256, 0, stream>>>(ei, flag, E);
  k_bhist<<<G, 256, 0, stream>>>(ei, flag, hist, E, NB, CPB);
  k_csum<<<NB, 64, 0, stream>>>(hist, total, NB, G);
  k_bscan<<<1, 1024, 0, stream>>>(total, bbase, NB);
  k_coff<<<NB, 64, 0, stream>>>(hist, bbase, NB, G);
  k_bscatter<<<G, 256, 0, stream>>>(ei, flag, hist, staging, E, NB, CPB);
  k_bfinal<<<NB, 256, 0, stream>>>(staging, bbase, row_start, sorted, N, NB, E);

  int gx = (N + 63) / 64;
  int aggGrid = (N + 3) / 4;

  // ---- layer 1: A = x (f32, lda=128), F=16 col-frags ----
  k_gemm2<0, 4, 1><<<dim3(gx, 2), 256, 0, stream>>>(x, Wt1, b1, bufP, q1, N, DIN, H1, Hp1, 16);
  k_agg<1, 2, 1, 1><<<aggGrid, 256, 0, stream>>>(bufP, q1, row_start, sorted, bufH1, N, H1, 128);

  // ---- layer 2: A = h1 (bf16, lda=128), F=10 ----
  k_gemm2<1, 4, 1><<<dim3(gx, 2), 256, 0, stream>>>(bufH1, Wt2, b2, bufP, q2, N, Kp12, H2, Hp2, 10);
  k_agg<1, 2, 1, 1><<<aggGrid, 256, 0, stream>>>(bufP, q2, row_start, sorted, bufH2, N, H2, 96);

  // ---- layer 3: A = h2 (bf16, lda=96), F=8 ----
  k_gemm2<1, 3, 0><<<dim3(gx, 1), 256, 0, stream>>>(bufH2, Wt3, b3, bufP, q3, N, Kp3, H3, Hp3, 8);
  k_agg<0, 1, 0, 0><<<aggGrid, 256, 0, stream>>>(bufP, q3, row_start, sorted, d_out, N, H3, 64);
}